// Round 16
// baseline (188.708 us; speedup 1.0000x reference)
//
#include <hip/hip_runtime.h>

#define NODE_DIM 32
#define EDGE_DIM 16
#define DD 48          // NODE_DIM + EDGE_DIM
#define OUT_DIM 32
#define MAXDEG 64      // bucket capacity (Poisson(16): max deg ~44)
#define NXCD 8
#define NPW 16         // nodes per wave (one MFMA M-tile for the node MLP)

typedef _Float16 f16x8 __attribute__((ext_vector_type(8)));
typedef float f32x4 __attribute__((ext_vector_type(4)));

// ---------------------------------------------------------------------------
// 1) prep (pure streaming): zero cursor; y -> fp16; ex -> fp16
// ---------------------------------------------------------------------------
__global__ __launch_bounds__(256)
void prep_kernel(int* __restrict__ cursor, int ZB, int NC,
                 const float* __restrict__ y, _Float16* __restrict__ yh, int CBy,
                 const float* __restrict__ ex, _Float16* __restrict__ exh,
                 int N, int E) {
    int b = blockIdx.x;
    if (b < ZB) {   // zero cursor: int4 per thread
        int i = (b * 256 + threadIdx.x) * 4;
        if (i < NC) *reinterpret_cast<int4*>(cursor + i) = make_int4(0, 0, 0, 0);
        return;
    }
    b -= ZB;
    if (b < CBy) {   // y -> fp16, 8 floats/thread
        size_t i = ((size_t)b * 256 + threadIdx.x) * 8;
        if (i < (size_t)N * NODE_DIM) {
            const float4* s0 = reinterpret_cast<const float4*>(y + i);
            const float4 a = s0[0], c = s0[1];
            f16x8 h = {(_Float16)a.x, (_Float16)a.y, (_Float16)a.z, (_Float16)a.w,
                       (_Float16)c.x, (_Float16)c.y, (_Float16)c.z, (_Float16)c.w};
            *reinterpret_cast<f16x8*>(yh + i) = h;
        }
        return;
    }
    b -= CBy;        // ex -> fp16, 8 floats/thread
    size_t i = ((size_t)b * 256 + threadIdx.x) * 8;
    if (i < (size_t)E * EDGE_DIM) {
        const float4* s0 = reinterpret_cast<const float4*>(ex + i);
        const float4 a = s0[0], c = s0[1];
        f16x8 h = {(_Float16)a.x, (_Float16)a.y, (_Float16)a.z, (_Float16)a.w,
                   (_Float16)c.x, (_Float16)c.y, (_Float16)c.z, (_Float16)c.w};
        *reinterpret_cast<f16x8*>(exh + i) = h;
    }
}

// ---------------------------------------------------------------------------
// 2) scatter, XCD-partitioned (unchanged, proven ~45us)
// ---------------------------------------------------------------------------
__global__ __launch_bounds__(256)
void scatter_kernel(const int* __restrict__ dst, const int* __restrict__ src,
                    int* __restrict__ cursor, int2* __restrict__ meta,
                    int E, int NP) {
    const int xcd = blockIdx.x & (NXCD - 1);
    const int c   = blockIdx.x >> 3;
    const int base = c * 2048 + threadIdx.x * 8;
    if (base >= E) return;

    int dv[8], sv[8];
    if (base + 8 <= E) {
        *reinterpret_cast<int4*>(dv)     = *reinterpret_cast<const int4*>(dst + base);
        *reinterpret_cast<int4*>(dv + 4) = *reinterpret_cast<const int4*>(dst + base + 4);
        *reinterpret_cast<int4*>(sv)     = *reinterpret_cast<const int4*>(src + base);
        *reinterpret_cast<int4*>(sv + 4) = *reinterpret_cast<const int4*>(src + base + 4);
    } else {
#pragma unroll
        for (int i = 0; i < 8; ++i) {
            dv[i] = (base + i < E) ? dst[base + i] : -1;
            sv[i] = (base + i < E) ? src[base + i] : 0;
        }
    }
#pragma unroll
    for (int i = 0; i < 8; ++i) {
        const int d = dv[i];
        if (d >= 0 && (d & (NXCD - 1)) == xcd && base + i < E) {
            int pos = atomicAdd(&cursor[xcd * NP + (d >> 3)], 1);
            if (pos < MAXDEG)
                meta[(size_t)d * MAXDEG + pos] = make_int2(base + i, sv[i]);
        }
    }
}

// ---------------------------------------------------------------------------
// 3) fused: each wave owns 16 nodes. Per node: MFMA edge-MLP -> shfl reduce
//    -> fp16 z-row into wave-private LDS (k48=1 activates b2, k49..63 = 0).
//    After 16 nodes: node MLP = 4 MFMAs (A = z tile, B = W2^T fragments),
//    8 coalesced stores. Zero block barriers; W1/W2 fragments built once/wave.
//    FIX vs r14: mlds pad entries MUST be written ({0,0}) — uninitialized
//    LDS garbage fed wild yh/exh addresses -> memory fault.
// ---------------------------------------------------------------------------
__global__ __launch_bounds__(256)
void fused_kernel(const _Float16* __restrict__ yh, const _Float16* __restrict__ exh,
                  const float* __restrict__ W1, const float* __restrict__ b1,
                  const float* __restrict__ W2, const float* __restrict__ b2,
                  const int* __restrict__ cursor, const int2* __restrict__ meta,
                  float* __restrict__ out, int N, int NP) {
    __shared__ int2 mlds[4][MAXDEG];
    __shared__ _Float16 zl[4][NPW][64];   // z rows: 48 z | 1.0 | zeros (K=64)

    const int wave = threadIdx.x >> 6;
    const int lane = threadIdx.x & 63;
    const int col = lane & 15;            // MFMA col / A-row index
    const int kg  = lane >> 4;            // k-group 0..3

    // --- edge-MLP B fragments (W1; b1 folded at kg==3, j==7 of Bhi) ---
    f16x8 Blo[3], Bhi[3];
#pragma unroll
    for (int t = 0; t < 3; ++t) {
        const float* wr = W1 + (size_t)(t * 16 + col) * DD;
#pragma unroll
        for (int j = 0; j < 8; ++j) {
            Blo[t][j] = (_Float16)wr[kg * 8 + j];
            Bhi[t][j] = (_Float16)0.f;
        }
        if (kg < 2) {
#pragma unroll
            for (int j = 0; j < 8; ++j)
                Bhi[t][j] = (_Float16)wr[NODE_DIM + kg * 8 + j];
        }
        if (kg == 3) Bhi[t][7] = (_Float16)b1[t * 16 + col];
    }

    // --- node-MLP B fragments: B[k][col] = W2[t*16+col][k]; b2 at k==48 ---
    f16x8 Wf[2][2];
#pragma unroll
    for (int t = 0; t < 2; ++t) {
#pragma unroll
        for (int c = 0; c < 2; ++c) {
            f16x8 v;
#pragma unroll
            for (int j = 0; j < 8; ++j) {
                const int k = c * 32 + kg * 8 + j;
                float w = 0.f;
                if (k < DD)       w = W2[(size_t)(t * 16 + col) * DD + k];
                else if (k == DD) w = b2[t * 16 + col];
                v[j] = (_Float16)w;
            }
            Wf[t][c] = v;
        }
    }

    const int nb0 = (blockIdx.x * 4 + wave) * NPW;

    for (int ni = 0; ni < NPW; ++ni) {
        const int n = nb0 + ni;
        const int dg = (n < N) ? cursor[(n & (NXCD - 1)) * NP + (n >> 3)] : 0;
        const int cnt = min(dg, MAXDEG);

        // unconditional write: pads -> {0,0} (safe dummy addresses)
        mlds[wave][lane] = (lane < cnt) ? meta[(size_t)n * MAXDEG + lane]
                                        : make_int2(0, 0);
        __builtin_amdgcn_wave_barrier();

        float pacc0 = 0.f, pacc1 = 0.f, pacc2 = 0.f;
        const int ngroups = (cnt + 15) >> 4;

        for (int g = 0; g < ngroups; ++g) {
            const bool valid = (g * 16 + col) < cnt;
            const int2 md = mlds[wave][g * 16 + col];
            const int eid = md.x, sv = md.y;

            f16x8 alo = *reinterpret_cast<const f16x8*>(
                yh + (size_t)sv * NODE_DIM + kg * 8);

            f16x8 ahi;
            if (kg < 2) {
                ahi = *reinterpret_cast<const f16x8*>(
                    exh + (size_t)eid * EDGE_DIM + kg * 8);
            } else {
#pragma unroll
                for (int j = 0; j < 8; ++j) ahi[j] = (_Float16)0.f;
                if (kg == 3) ahi[7] = (_Float16)1.f;   // activates b1
            }

            if (!valid) {   // pads contribute exactly 0
#pragma unroll
                for (int j = 0; j < 8; ++j) { alo[j] = (_Float16)0.f; ahi[j] = (_Float16)0.f; }
            }

#pragma unroll
            for (int t = 0; t < 3; ++t) {
                f32x4 c = {0.f, 0.f, 0.f, 0.f};
                c = __builtin_amdgcn_mfma_f32_16x16x32_f16(alo, Blo[t], c, 0, 0, 0);
                c = __builtin_amdgcn_mfma_f32_16x16x32_f16(ahi, Bhi[t], c, 0, 0, 0);
#pragma unroll
                for (int r = 0; r < 4; ++r) {
                    const float v = fmaxf(c[r], 0.f);  // b1 already inside
                    if (t == 0) pacc0 += v;
                    else if (t == 1) pacc1 += v;
                    else pacc2 += v;
                }
            }
        }

        pacc0 += __shfl_xor(pacc0, 16); pacc0 += __shfl_xor(pacc0, 32);
        pacc1 += __shfl_xor(pacc1, 16); pacc1 += __shfl_xor(pacc1, 32);
        pacc2 += __shfl_xor(pacc2, 16); pacc2 += __shfl_xor(pacc2, 32);

        if (n < N) {
            const float inv = (dg > 0) ? 1.f / (float)dg : 0.f;
            if (lane < 16) {
                zl[wave][ni][lane]      = (_Float16)(pacc0 * inv);
                zl[wave][ni][lane + 16] = (_Float16)(pacc1 * inv);
                zl[wave][ni][lane + 32] = (_Float16)(pacc2 * inv);
            }
            if (lane < 8) {   // k=48 -> 1.0 (bias activator), k=49..63 -> 0
                const unsigned int v = (lane == 0) ? 0x00003C00u : 0u; // {1.0h, 0h}
                *reinterpret_cast<unsigned int*>(&zl[wave][ni][48 + lane * 2]) = v;
            }
        } else if (lane < 32) {   // tail: zero the row so the MFMA sees no NaNs
            *reinterpret_cast<unsigned int*>(&zl[wave][ni][lane * 2]) = 0u;
        }
        __builtin_amdgcn_wave_barrier();
    }

    // --- batched node MLP: h[16 nodes][32] = ReLU(z * W2^T + b2) ---
    __builtin_amdgcn_wave_barrier();
    const _Float16* zr = &zl[wave][col][0];
    const f16x8 A0 = *reinterpret_cast<const f16x8*>(zr + kg * 8);        // k 0..31
    const f16x8 A1 = *reinterpret_cast<const f16x8*>(zr + 32 + kg * 8);   // k 32..63

#pragma unroll
    for (int t = 0; t < 2; ++t) {
        f32x4 h = {0.f, 0.f, 0.f, 0.f};
        h = __builtin_amdgcn_mfma_f32_16x16x32_f16(A0, Wf[t][0], h, 0, 0, 0);
        h = __builtin_amdgcn_mfma_f32_16x16x32_f16(A1, Wf[t][1], h, 0, 0, 0);
#pragma unroll
        for (int r = 0; r < 4; ++r) {
            const int node = nb0 + kg * 4 + r;     // C row = node-in-batch
            if (node < N)
                out[(size_t)node * OUT_DIM + t * 16 + col] = fmaxf(h[r], 0.f);
        }
    }
}

// ---------------------------------------------------------------------------
extern "C" void kernel_launch(void* const* d_in, const int* in_sizes, int n_in,
                              void* d_out, int out_size, void* d_ws, size_t ws_size,
                              hipStream_t stream) {
    const float* y  = (const float*)d_in[0];
    const float* ex = (const float*)d_in[1];
    const float* W1 = (const float*)d_in[2];
    const float* b1 = (const float*)d_in[3];
    const float* W2 = (const float*)d_in[4];
    const float* b2 = (const float*)d_in[5];
    const int* src  = (const int*)d_in[6];
    const int* dst  = (const int*)d_in[7];

    const int N = in_sizes[0] / NODE_DIM;   // 100000
    const int E = in_sizes[6];              // 1600000
    const int NP = (N + NXCD - 1) / NXCD;   // per-XCD cursor stride
    const int NC = ((NXCD * NP + 3) / 4) * 4;

    // workspace: cursor | meta | yh | exh  (~83 MB)
    int* cursor = (int*)d_ws;                                   // NC ints
    size_t off  = ((size_t)NC * sizeof(int) + 255) & ~(size_t)255;
    int2* meta  = (int2*)((char*)d_ws + off);                   // N x MAXDEG int2
    _Float16* yh = (_Float16*)((char*)meta + (size_t)N * MAXDEG * sizeof(int2));
    _Float16* exh = (_Float16*)((char*)yh + (size_t)N * NODE_DIM * sizeof(_Float16));

    const int ZB  = (NC / 4 + 255) / 256;
    const int CBy = (N * NODE_DIM / 8 + 255) / 256;
    const int CBe = (E * EDGE_DIM / 8 + 255) / 256;

    prep_kernel<<<ZB + CBy + CBe, 256, 0, stream>>>(cursor, ZB, NC,
                                                    y, yh, CBy, ex, exh, N, E);

    const int K = (E + 2047) / 2048;        // chunks; 8 blocks per chunk
    scatter_kernel<<<K * NXCD, 256, 0, stream>>>(dst, src, cursor, meta, E, NP);

    const int NB = (N + NPW * 4 - 1) / (NPW * 4);   // 16 nodes/wave, 4 waves/block
    fused_kernel<<<NB, 256, 0, stream>>>(yh, exh, W1, b1, W2, b2,
                                         cursor, meta, (float*)d_out, N, NP);
}

// Round 17
// 185.712 us; speedup vs baseline: 1.0161x; 1.0161x over previous
//
#include <hip/hip_runtime.h>

#define NODE_DIM 32
#define EDGE_DIM 16
#define DD 48          // NODE_DIM + EDGE_DIM
#define OUT_DIM 32
#define MAXDEG 64      // bucket capacity (Poisson(16): max deg ~44)
#define NXCD 8
#define NPW 16         // nodes per wave (one MFMA M-tile for the node MLP)

typedef _Float16 f16x8 __attribute__((ext_vector_type(8)));
typedef float f32x4 __attribute__((ext_vector_type(4)));

// ---------------------------------------------------------------------------
// 1) prep (pure streaming): zero cursor; y -> fp16; ex -> fp16
// ---------------------------------------------------------------------------
__global__ __launch_bounds__(256)
void prep_kernel(int* __restrict__ cursor, int ZB, int NC,
                 const float* __restrict__ y, _Float16* __restrict__ yh, int CBy,
                 const float* __restrict__ ex, _Float16* __restrict__ exh,
                 int N, int E) {
    int b = blockIdx.x;
    if (b < ZB) {   // zero cursor: int4 per thread
        int i = (b * 256 + threadIdx.x) * 4;
        if (i < NC) *reinterpret_cast<int4*>(cursor + i) = make_int4(0, 0, 0, 0);
        return;
    }
    b -= ZB;
    if (b < CBy) {   // y -> fp16, 8 floats/thread
        size_t i = ((size_t)b * 256 + threadIdx.x) * 8;
        if (i < (size_t)N * NODE_DIM) {
            const float4* s0 = reinterpret_cast<const float4*>(y + i);
            const float4 a = s0[0], c = s0[1];
            f16x8 h = {(_Float16)a.x, (_Float16)a.y, (_Float16)a.z, (_Float16)a.w,
                       (_Float16)c.x, (_Float16)c.y, (_Float16)c.z, (_Float16)c.w};
            *reinterpret_cast<f16x8*>(yh + i) = h;
        }
        return;
    }
    b -= CBy;        // ex -> fp16, 8 floats/thread
    size_t i = ((size_t)b * 256 + threadIdx.x) * 8;
    if (i < (size_t)E * EDGE_DIM) {
        const float4* s0 = reinterpret_cast<const float4*>(ex + i);
        const float4 a = s0[0], c = s0[1];
        f16x8 h = {(_Float16)a.x, (_Float16)a.y, (_Float16)a.z, (_Float16)a.w,
                   (_Float16)c.x, (_Float16)c.y, (_Float16)c.z, (_Float16)c.w};
        *reinterpret_cast<f16x8*>(exh + i) = h;
    }
}

// ---------------------------------------------------------------------------
// 2) scatter, XCD-partitioned (unchanged, proven ~45us)
// ---------------------------------------------------------------------------
__global__ __launch_bounds__(256)
void scatter_kernel(const int* __restrict__ dst, const int* __restrict__ src,
                    int* __restrict__ cursor, int2* __restrict__ meta,
                    int E, int NP) {
    const int xcd = blockIdx.x & (NXCD - 1);
    const int c   = blockIdx.x >> 3;
    const int base = c * 2048 + threadIdx.x * 8;
    if (base >= E) return;

    int dv[8], sv[8];
    if (base + 8 <= E) {
        *reinterpret_cast<int4*>(dv)     = *reinterpret_cast<const int4*>(dst + base);
        *reinterpret_cast<int4*>(dv + 4) = *reinterpret_cast<const int4*>(dst + base + 4);
        *reinterpret_cast<int4*>(sv)     = *reinterpret_cast<const int4*>(src + base);
        *reinterpret_cast<int4*>(sv + 4) = *reinterpret_cast<const int4*>(src + base + 4);
    } else {
#pragma unroll
        for (int i = 0; i < 8; ++i) {
            dv[i] = (base + i < E) ? dst[base + i] : -1;
            sv[i] = (base + i < E) ? src[base + i] : 0;
        }
    }
#pragma unroll
    for (int i = 0; i < 8; ++i) {
        const int d = dv[i];
        if (d >= 0 && (d & (NXCD - 1)) == xcd && base + i < E) {
            int pos = atomicAdd(&cursor[xcd * NP + (d >> 3)], 1);
            if (pos < MAXDEG)
                meta[(size_t)d * MAXDEG + pos] = make_int2(base + i, sv[i]);
        }
    }
}

// ---------------------------------------------------------------------------
// 3) fused: each wave owns 16 nodes. ALL latency batched up front:
//    one lane-parallel cursor load (degrees via shfl) + 16 independent
//    masked meta loads staging every bucket into LDS. Then per node:
//    MFMA edge-MLP from LDS meta + yh/exh gathers -> shfl reduce ->
//    fp16 z-row (k48=1 activates b2). Epilogue: node MLP = 4 MFMAs,
//    coalesced stores. Zero block barriers.
// ---------------------------------------------------------------------------
__global__ __launch_bounds__(256)
void fused_kernel(const _Float16* __restrict__ yh, const _Float16* __restrict__ exh,
                  const float* __restrict__ W1, const float* __restrict__ b1,
                  const float* __restrict__ W2, const float* __restrict__ b2,
                  const int* __restrict__ cursor, const int2* __restrict__ meta,
                  float* __restrict__ out, int N, int NP) {
    __shared__ int2 mlds[4][NPW][MAXDEG];  // 32 KB: all 16 buckets per wave
    __shared__ _Float16 zl[4][NPW][64];    // 8 KB: z rows (48 z | 1.0 | 0s)

    const int wave = threadIdx.x >> 6;
    const int lane = threadIdx.x & 63;
    const int col = lane & 15;            // MFMA col / A-row index
    const int kg  = lane >> 4;            // k-group 0..3

    // --- edge-MLP B fragments (W1; b1 folded at kg==3, j==7 of Bhi) ---
    f16x8 Blo[3], Bhi[3];
#pragma unroll
    for (int t = 0; t < 3; ++t) {
        const float* wr = W1 + (size_t)(t * 16 + col) * DD;
#pragma unroll
        for (int j = 0; j < 8; ++j) {
            Blo[t][j] = (_Float16)wr[kg * 8 + j];
            Bhi[t][j] = (_Float16)0.f;
        }
        if (kg < 2) {
#pragma unroll
            for (int j = 0; j < 8; ++j)
                Bhi[t][j] = (_Float16)wr[NODE_DIM + kg * 8 + j];
        }
        if (kg == 3) Bhi[t][7] = (_Float16)b1[t * 16 + col];
    }

    // --- node-MLP B fragments: B[k][col] = W2[t*16+col][k]; b2 at k==48 ---
    f16x8 Wf[2][2];
#pragma unroll
    for (int t = 0; t < 2; ++t) {
#pragma unroll
        for (int c = 0; c < 2; ++c) {
            f16x8 v;
#pragma unroll
            for (int j = 0; j < 8; ++j) {
                const int k = c * 32 + kg * 8 + j;
                float w = 0.f;
                if (k < DD)       w = W2[(size_t)(t * 16 + col) * DD + k];
                else if (k == DD) w = b2[t * 16 + col];
                v[j] = (_Float16)w;
            }
            Wf[t][c] = v;
        }
    }

    const int nb0 = (blockIdx.x * 4 + wave) * NPW;

    // --- batched latency: one cursor load for all 16 nodes ---
    int dgv = 0;
    if (lane < NPW) {
        const int n = nb0 + lane;
        if (n < N) dgv = cursor[(n & (NXCD - 1)) * NP + (n >> 3)];
    }

    // --- stage ALL 16 buckets: 16 independent masked loads per lane ---
#pragma unroll
    for (int ni = 0; ni < NPW; ++ni) {
        const int cnt_i = min(__shfl(dgv, ni), MAXDEG);
        const int n = nb0 + ni;
        mlds[wave][ni][lane] = (lane < cnt_i && n < N)
                                   ? meta[(size_t)n * MAXDEG + lane]
                                   : make_int2(0, 0);
    }
    __builtin_amdgcn_wave_barrier();

    for (int ni = 0; ni < NPW; ++ni) {
        const int n = nb0 + ni;
        const int dg = __shfl(dgv, ni);
        const int cnt = min(dg, MAXDEG);

        float pacc0 = 0.f, pacc1 = 0.f, pacc2 = 0.f;
        const int ngroups = (cnt + 15) >> 4;

        for (int g = 0; g < ngroups; ++g) {
            const bool valid = (g * 16 + col) < cnt;
            const int2 md = mlds[wave][ni][g * 16 + col];
            const int eid = md.x, sv = md.y;

            f16x8 alo = *reinterpret_cast<const f16x8*>(
                yh + (size_t)sv * NODE_DIM + kg * 8);

            f16x8 ahi;
            if (kg < 2) {
                ahi = *reinterpret_cast<const f16x8*>(
                    exh + (size_t)eid * EDGE_DIM + kg * 8);
            } else {
#pragma unroll
                for (int j = 0; j < 8; ++j) ahi[j] = (_Float16)0.f;
                if (kg == 3) ahi[7] = (_Float16)1.f;   // activates b1
            }

            if (!valid) {   // pads contribute exactly 0
#pragma unroll
                for (int j = 0; j < 8; ++j) { alo[j] = (_Float16)0.f; ahi[j] = (_Float16)0.f; }
            }

#pragma unroll
            for (int t = 0; t < 3; ++t) {
                f32x4 c = {0.f, 0.f, 0.f, 0.f};
                c = __builtin_amdgcn_mfma_f32_16x16x32_f16(alo, Blo[t], c, 0, 0, 0);
                c = __builtin_amdgcn_mfma_f32_16x16x32_f16(ahi, Bhi[t], c, 0, 0, 0);
#pragma unroll
                for (int r = 0; r < 4; ++r) {
                    const float v = fmaxf(c[r], 0.f);  // b1 already inside
                    if (t == 0) pacc0 += v;
                    else if (t == 1) pacc1 += v;
                    else pacc2 += v;
                }
            }
        }

        pacc0 += __shfl_xor(pacc0, 16); pacc0 += __shfl_xor(pacc0, 32);
        pacc1 += __shfl_xor(pacc1, 16); pacc1 += __shfl_xor(pacc1, 32);
        pacc2 += __shfl_xor(pacc2, 16); pacc2 += __shfl_xor(pacc2, 32);

        if (n < N) {
            const float inv = (dg > 0) ? 1.f / (float)dg : 0.f;
            if (lane < 16) {
                zl[wave][ni][lane]      = (_Float16)(pacc0 * inv);
                zl[wave][ni][lane + 16] = (_Float16)(pacc1 * inv);
                zl[wave][ni][lane + 32] = (_Float16)(pacc2 * inv);
            }
            if (lane < 8) {   // k=48 -> 1.0 (bias activator), k=49..63 -> 0
                const unsigned int v = (lane == 0) ? 0x00003C00u : 0u; // {1.0h, 0h}
                *reinterpret_cast<unsigned int*>(&zl[wave][ni][48 + lane * 2]) = v;
            }
        } else if (lane < 32) {   // tail: zero the row so the MFMA sees no NaNs
            *reinterpret_cast<unsigned int*>(&zl[wave][ni][lane * 2]) = 0u;
        }
        __builtin_amdgcn_wave_barrier();
    }

    // --- batched node MLP: h[16 nodes][32] = ReLU(z * W2^T + b2) ---
    __builtin_amdgcn_wave_barrier();
    const _Float16* zr = &zl[wave][col][0];
    const f16x8 A0 = *reinterpret_cast<const f16x8*>(zr + kg * 8);        // k 0..31
    const f16x8 A1 = *reinterpret_cast<const f16x8*>(zr + 32 + kg * 8);   // k 32..63

#pragma unroll
    for (int t = 0; t < 2; ++t) {
        f32x4 h = {0.f, 0.f, 0.f, 0.f};
        h = __builtin_amdgcn_mfma_f32_16x16x32_f16(A0, Wf[t][0], h, 0, 0, 0);
        h = __builtin_amdgcn_mfma_f32_16x16x32_f16(A1, Wf[t][1], h, 0, 0, 0);
#pragma unroll
        for (int r = 0; r < 4; ++r) {
            const int node = nb0 + kg * 4 + r;     // C row = node-in-batch
            if (node < N)
                out[(size_t)node * OUT_DIM + t * 16 + col] = fmaxf(h[r], 0.f);
        }
    }
}

// ---------------------------------------------------------------------------
extern "C" void kernel_launch(void* const* d_in, const int* in_sizes, int n_in,
                              void* d_out, int out_size, void* d_ws, size_t ws_size,
                              hipStream_t stream) {
    const float* y  = (const float*)d_in[0];
    const float* ex = (const float*)d_in[1];
    const float* W1 = (const float*)d_in[2];
    const float* b1 = (const float*)d_in[3];
    const float* W2 = (const float*)d_in[4];
    const float* b2 = (const float*)d_in[5];
    const int* src  = (const int*)d_in[6];
    const int* dst  = (const int*)d_in[7];

    const int N = in_sizes[0] / NODE_DIM;   // 100000
    const int E = in_sizes[6];              // 1600000
    const int NP = (N + NXCD - 1) / NXCD;   // per-XCD cursor stride
    const int NC = ((NXCD * NP + 3) / 4) * 4;

    // workspace: cursor | meta | yh | exh  (~83 MB)
    int* cursor = (int*)d_ws;                                   // NC ints
    size_t off  = ((size_t)NC * sizeof(int) + 255) & ~(size_t)255;
    int2* meta  = (int2*)((char*)d_ws + off);                   // N x MAXDEG int2
    _Float16* yh = (_Float16*)((char*)meta + (size_t)N * MAXDEG * sizeof(int2));
    _Float16* exh = (_Float16*)((char*)yh + (size_t)N * NODE_DIM * sizeof(_Float16));

    const int ZB  = (NC / 4 + 255) / 256;
    const int CBy = (N * NODE_DIM / 8 + 255) / 256;
    const int CBe = (E * EDGE_DIM / 8 + 255) / 256;

    prep_kernel<<<ZB + CBy + CBe, 256, 0, stream>>>(cursor, ZB, NC,
                                                    y, yh, CBy, ex, exh, N, E);

    const int K = (E + 2047) / 2048;        // chunks; 8 blocks per chunk
    scatter_kernel<<<K * NXCD, 256, 0, stream>>>(dst, src, cursor, meta, E, NP);

    const int NB = (N + NPW * 4 - 1) / (NPW * 4);   // 16 nodes/wave, 4 waves/block
    fused_kernel<<<NB, 256, 0, stream>>>(yh, exh, W1, b1, W2, b2,
                                         cursor, meta, (float*)d_out, N, NP);
}